// Round 9
// baseline (135.973 us; speedup 1.0000x reference)
//
#include <hip/hip_runtime.h>

// HeadC fused: grouped 1x1-conv projections (q,k,v) + causal softmax attention.
// B=4096, T=50, N_EMBED=600, HEAD_SIZE=100, CHUNK=6. One block per batch.
// Scores/PV via mfma_f32_16x16x32_bf16; LDS tiles bf16, granule XOR swizzle.
// R6: LDS 48.1->39.0 KB (P overlays dead q region; scores buffered in regs
// across a barrier) => 4 blocks/CU, 16 waves/CU.

#define BATCH 4096
#define TT 50
#define HH 100
#define CC 600

typedef __attribute__((ext_vector_type(8))) short short8;
typedef __attribute__((ext_vector_type(4))) short short4v;
typedef __attribute__((ext_vector_type(4))) float f32x4;
typedef unsigned short ushort_t;

constexpr int NTHR = 256;
constexpr int NWAVES = NTHR / 64;  // 4
constexpr float kScale = 0.04082482904638630163f;  // 600^-0.5 (folded into q)

// LDS (ushort units), 19968 us = 39936 B = 78*512 -> 4 blocks/CU.
//   s_q @ 0      [50][128]  (dead after scores; P [64][64] overlays at 0)
//   s_k @ 6400   [50][128]
//   s_vT@ 12800  [112][64]  (rows 100..111 stay zero -> PV pad reads are 0)
// Spill-reads (frag rows beyond live range) land in the next region: finite
// junk -> only discarded D rows (t>=50) / softmax-masked cols (s>t) polluted.
constexpr int OQ = 0, OKk = 6400, OV = 12800, OP = 0, LDS_US = 19968;

__device__ __forceinline__ ushort_t f2bf(float f) {  // RNE f32->bf16 (finite)
    unsigned u = __float_as_uint(f);
    u += 0x7FFFu + ((u >> 16) & 1u);
    return (ushort_t)(u >> 16);
}
__device__ __forceinline__ float bf2f(ushort_t h) {
    return __uint_as_float(((unsigned)h) << 16);
}

__global__ __launch_bounds__(NTHR, 4) void headc_fused(
    const float* __restrict__ x,
    const float* __restrict__ wq,
    const float* __restrict__ wk,
    const float* __restrict__ wv,
    float* __restrict__ out)
{
    __shared__ __align__(16) ushort_t lds[LDS_US];

    const int b = blockIdx.x;
    const int tid = threadIdx.x;
    const float* xb = x + (size_t)b * (TT * CC);

    // ---- phase 0: zero q,k,vT (pads must be 0 for MFMA K-dims) ----
    for (int i = tid; i < LDS_US / 8; i += NTHR) {
        short8 z = {0, 0, 0, 0, 0, 0, 0, 0};
        *reinterpret_cast<short8*>(lds + i * 8) = z;
    }
    __syncthreads();

    // ---- phase 1: projections. item = (t-quad, h-pair); 13*50 = 650 items.
    // All 12 x-loads + 9 weight-loads issued independently (MLP), then FMAs.
    for (int j = tid; j < 650; j += NTHR) {
        const int qd = j / 50;          // 0..12
        const int hp = j - qd * 50;
        const int h0 = hp * 2;
        const int tbase = qd * 4;

        float4 xr[4][3];
        #pragma unroll
        for (int r = 0; r < 4; ++r) {
            const int tc = (tbase + r < TT) ? (tbase + r) : (TT - 1);
            const float* xp = xb + tc * CC + h0 * 6;   // 48B/lane, coalesced
            xr[r][0] = *(const float4*)xp;
            xr[r][1] = *(const float4*)(xp + 4);
            xr[r][2] = *(const float4*)(xp + 8);
        }
        const float4 wqa = *(const float4*)(wq + h0 * 6);
        const float4 wqb = *(const float4*)(wq + h0 * 6 + 4);
        const float4 wqc = *(const float4*)(wq + h0 * 6 + 8);
        const float4 wka = *(const float4*)(wk + h0 * 6);
        const float4 wkb = *(const float4*)(wk + h0 * 6 + 4);
        const float4 wkc = *(const float4*)(wk + h0 * 6 + 8);
        const float4 wva = *(const float4*)(wv + h0 * 6);
        const float4 wvb = *(const float4*)(wv + h0 * 6 + 4);
        const float4 wvc = *(const float4*)(wv + h0 * 6 + 8);

        short4v vp0 = {0, 0, 0, 0};
        short4v vp1 = {0, 0, 0, 0};
        #pragma unroll
        for (int r = 0; r < 4; ++r) {
            const int t = tbase + r;
            const float4 xa = xr[r][0], xm = xr[r][1], xc = xr[r][2];
            float q0 = xa.x*wqa.x + xa.y*wqa.y + xa.z*wqa.z + xa.w*wqa.w + xm.x*wqb.x + xm.y*wqb.y;
            float q1 = xm.z*wqb.z + xm.w*wqb.w + xc.x*wqc.x + xc.y*wqc.y + xc.z*wqc.z + xc.w*wqc.w;
            float k0 = xa.x*wka.x + xa.y*wka.y + xa.z*wka.z + xa.w*wka.w + xm.x*wkb.x + xm.y*wkb.y;
            float k1 = xm.z*wkb.z + xm.w*wkb.w + xc.x*wkc.x + xc.y*wkc.y + xc.z*wkc.z + xc.w*wkc.w;
            float v0 = xa.x*wva.x + xa.y*wva.y + xa.z*wva.z + xa.w*wva.w + xm.x*wvb.x + xm.y*wvb.y;
            float v1 = xm.z*wvb.z + xm.w*wvb.w + xc.x*wvc.x + xc.y*wvc.y + xc.z*wvc.z + xc.w*wvc.w;
            q0 *= kScale; q1 *= kScale;   // fold score scale into q
            if (t < TT) {
                const int qg = (((h0 >> 3) ^ (t & 7)) << 3) + (h0 & 7);
                *reinterpret_cast<unsigned*>(lds + OQ  + t * 128 + qg) =
                    (unsigned)f2bf(q0) | ((unsigned)f2bf(q1) << 16);
                *reinterpret_cast<unsigned*>(lds + OKk + t * 128 + qg) =
                    (unsigned)f2bf(k0) | ((unsigned)f2bf(k1) << 16);
                vp0[r] = (short)f2bf(v0);
                vp1[r] = (short)f2bf(v1);
            }
        }
        const int g = qd >> 1, half = (qd & 1) * 4;
        *reinterpret_cast<short4v*>(lds + OV + h0 * 64 + ((g ^ (h0 & 7)) << 3) + half) = vp0;
        *reinterpret_cast<short4v*>(lds + OV + (h0 + 1) * 64 + ((g ^ ((h0 + 1) & 7)) << 3) + half) = vp1;
    }
    __syncthreads();

    const int wv_ = tid >> 6;
    const int lane = tid & 63;
    const int l15 = lane & 15, l4 = lane >> 4;

    // ---- phase 2a: scores S = Q*K^T, 10 causal tiles, accs held in regs ----
    f32x4 sacc[3];
    #pragma unroll
    for (int ii = 0; ii < 3; ++ii) {
        const int p = wv_ + ii * NWAVES;
        sacc[ii] = (f32x4){0.f, 0.f, 0.f, 0.f};
        if (p < 10) {
            const int tm = (p >= 6) ? 3 : (p >= 3) ? 2 : (p >= 1) ? 1 : 0;
            const int sn = p - tm * (tm + 1) / 2;
            const int ar = tm * 16 + l15;   // q row (>=50: junk -> discarded)
            const int br = sn * 16 + l15;   // k row
            f32x4 acc = {0.f, 0.f, 0.f, 0.f};
            #pragma unroll
            for (int kk = 0; kk < 4; ++kk) {
                const int g = kk * 4 + l4;
                const short8 a  = *reinterpret_cast<const short8*>(lds + OQ  + ar * 128 + ((g ^ (ar & 7)) << 3));
                const short8 bb = *reinterpret_cast<const short8*>(lds + OKk + br * 128 + ((g ^ (br & 7)) << 3));
                acc = __builtin_amdgcn_mfma_f32_16x16x32_bf16(a, bb, acc, 0, 0, 0);
            }
            sacc[ii] = acc;
        }
    }
    __syncthreads();   // all q reads done -> safe to overlay P on q region

    // ---- phase 2b: write P (bf16) into dead q region ----
    #pragma unroll
    for (int ii = 0; ii < 3; ++ii) {
        const int p = wv_ + ii * NWAVES;
        if (p < 10) {
            const int tm = (p >= 6) ? 3 : (p >= 3) ? 2 : (p >= 1) ? 1 : 0;
            const int sn = p - tm * (tm + 1) / 2;
            const int row0 = tm * 16 + l4 * 4;
            const int col = sn * 16 + l15;
            #pragma unroll
            for (int r = 0; r < 4; ++r) {
                const int row = row0 + r;
                lds[OP + row * 64 + (((col >> 3) ^ (row & 7)) << 3) + (col & 7)] = f2bf(sacc[ii][r]);
            }
        }
    }
    __syncthreads();

    // ---- phase 3: softmax, one lane per row, in place ----
    if (tid < TT) {
        const int t = tid;
        float vv[64];
        float mx = -3.4e38f;
        #pragma unroll
        for (int g = 0; g < 8; ++g) {
            const short8 pk = *reinterpret_cast<const short8*>(lds + OP + t * 64 + ((g ^ (t & 7)) << 3));
            #pragma unroll
            for (int jj = 0; jj < 8; ++jj) {
                const int s = g * 8 + jj;
                const float f = bf2f((ushort_t)pk[jj]);
                vv[s] = f;
                mx = (s <= t) ? fmaxf(mx, f) : mx;
            }
        }
        float sum = 0.f;
        #pragma unroll
        for (int s = 0; s < 64; ++s) {
            const float e = (s <= t) ? __expf(vv[s] - mx) : 0.f;
            vv[s] = e;
            sum += e;
        }
        const float inv = 1.f / sum;
        #pragma unroll
        for (int g = 0; g < 8; ++g) {
            short8 w;
            #pragma unroll
            for (int jj = 0; jj < 8; ++jj) w[jj] = (short)f2bf(vv[g * 8 + jj] * inv);
            *reinterpret_cast<short8*>(lds + OP + t * 64 + ((g ^ (t & 7)) << 3)) = w;
        }
    }
    __syncthreads();

    // ---- phase 4: O = P*V via MFMA, 4x7 tiles, K = 64 (P zeros past t) ----
    float* ob = out + (size_t)b * (TT * HH);
    for (int p = wv_; p < 28; p += NWAVES) {
        const int tm = p / 7, hn = p - tm * 7;
        f32x4 acc = {0.f, 0.f, 0.f, 0.f};
        const int ar = tm * 16 + l15;   // p row
        const int br = hn * 16 + l15;   // vT row (h); rows 100..111 are zeros
        #pragma unroll
        for (int kk = 0; kk < 2; ++kk) {
            const int g = kk * 4 + l4;
            const short8 a  = *reinterpret_cast<const short8*>(lds + OP + ar * 64 + ((g ^ (ar & 7)) << 3));
            const short8 bb = *reinterpret_cast<const short8*>(lds + OV + br * 64 + ((g ^ (br & 7)) << 3));
            acc = __builtin_amdgcn_mfma_f32_16x16x32_bf16(a, bb, acc, 0, 0, 0);
        }
        const int h = hn * 16 + l15;
        const int t0 = tm * 16 + l4 * 4;
        if (h < HH) {
            #pragma unroll
            for (int r = 0; r < 4; ++r) {
                const int t = t0 + r;
                if (t < TT) ob[t * HH + h] = acc[r];
            }
        }
    }
}

extern "C" void kernel_launch(void* const* d_in, const int* in_sizes, int n_in,
                              void* d_out, int out_size, void* d_ws, size_t ws_size,
                              hipStream_t stream) {
    const float* x  = (const float*)d_in[0];
    const float* wq = (const float*)d_in[1];
    const float* wk = (const float*)d_in[2];
    const float* wv = (const float*)d_in[3];
    float* out = (float*)d_out;
    headc_fused<<<dim3(BATCH), dim3(NTHR), 0, stream>>>(x, wq, wk, wv, out);
}

// Round 10
// 121.457 us; speedup vs baseline: 1.1195x; 1.1195x over previous
//
#include <hip/hip_runtime.h>
#include <hip/hip_bf16.h>

// HeadC fused: grouped 1x1-conv projections (q,k,v) + causal softmax attention.
// B=4096, T=50, N_EMBED=600, HEAD_SIZE=100, CHUNK=6. One block per batch.
// Scores/PV via mfma_f32_16x16x32_bf16; LDS tiles bf16, granule XOR swizzle.
// R7: serial-skeleton cuts — 3 barriers (was 5), all-wave group softmax,
// weights hoisted once per thread, pad-only LDS zeroing folded into phase 1.

#define BATCH 4096
#define TT 50
#define HH 100
#define CC 600

typedef __attribute__((ext_vector_type(8))) short short8;
typedef __attribute__((ext_vector_type(4))) short short4v;
typedef __attribute__((ext_vector_type(4))) float f32x4;
typedef unsigned short ushort_t;

constexpr int NTHR = 256;
constexpr int NWAVES = 4;
constexpr float kScale = 0.04082482904638630163f;  // 600^-0.5 (folded into q)

// LDS (ushort units), 24064 us = 48128 B -> 3 blocks/CU.
//   s_q @ 0      [50][128]  (frag rows 50..63 spill into k region: finite junk)
//   s_k @ 6400   [50][128]  (frag rows 50..63 spill into vT region: finite junk)
//   s_vT@ 12800  [112][64]  (vT[h][t]; cols 52..63 + rows 100..111 zeroed)
//   s_p @ 19968  [64][64]   (scores -> probabilities in place; rows 50..63 junk,
//                            feeding only discarded D rows t>=50)
constexpr int OQ = 0, OKk = 6400, OV = 12800, OP = 19968, LDS_US = 24064;

__device__ __forceinline__ ushort_t f2bf(float f) {
    return __builtin_bit_cast(ushort_t, __float2bfloat16(f));
}
__device__ __forceinline__ float bf2f(ushort_t h) {
    return __uint_as_float(((unsigned)h) << 16);
}

__global__ __launch_bounds__(NTHR, 3) void headc_fused(
    const float* __restrict__ x,
    const float* __restrict__ wq,
    const float* __restrict__ wk,
    const float* __restrict__ wv,
    float* __restrict__ out)
{
    __shared__ __align__(16) ushort_t lds[LDS_US];

    const int b = blockIdx.x;
    const int tid = threadIdx.x;
    const float* xb = x + (size_t)b * (TT * CC);

    // ---- phase 1a: zero only the pad regions (no dedicated barrier) ----
    {
        const short8 z8 = {0, 0, 0, 0, 0, 0, 0, 0};
        const short4v z4 = {0, 0, 0, 0};
        if (tid < 100) {
            // q/k K-pad cols 100..127 (logical granule 12 upper half + 13..15)
            const int arr = tid / 50;
            const int r = tid % 50;
            const int base = (arr ? OKk : OQ) + r * 128;
            *reinterpret_cast<short4v*>(lds + base + ((12 ^ (r & 7)) << 3) + 4) = z4;
            *reinterpret_cast<short8*>(lds + base + ((13 ^ (r & 7)) << 3)) = z8;
            *reinterpret_cast<short8*>(lds + base + ((14 ^ (r & 7)) << 3)) = z8;
            *reinterpret_cast<short8*>(lds + base + ((15 ^ (r & 7)) << 3)) = z8;
            // vT K-pad cols t=52..63 (granule 6 upper half + granule 7), rows tid, tid+100
            #pragma unroll
            for (int rr = 0; rr < 2; ++rr) {
                const int vr = tid + rr * 100;  // rows 0..99 (vr<100) ; skip 100..199
                if (vr < 100) {
                    *reinterpret_cast<short4v*>(lds + OV + vr * 64 + ((6 ^ (vr & 7)) << 3) + 4) = z4;
                    *reinterpret_cast<short8*>(lds + OV + vr * 64 + ((7 ^ (vr & 7)) << 3)) = z8;
                }
            }
        } else if (tid < 196) {
            // vT rows 100..111 fully zero (PV B-frag rows beyond h=99)
            const int idx = tid - 100;
            const int r = 100 + (idx >> 3);
            const int gr = idx & 7;
            *reinterpret_cast<short8*>(lds + OV + r * 64 + gr * 8) = z8;
        } else if (tid < 246) {
            // vT K-pad for rows 50..99 handled above only for vr<100 via tid<100;
            // rows 50..99 need it too: tid 196..245 -> rows 50..99
            const int vr = tid - 196 + 50;
            *reinterpret_cast<short4v*>(lds + OV + vr * 64 + ((6 ^ (vr & 7)) << 3) + 4) = z4;
            *reinterpret_cast<short8*>(lds + OV + vr * 64 + ((7 ^ (vr & 7)) << 3)) = z8;
        }
    }

    // ---- phase 1b: projections. hp pinned per thread (weights loaded once);
    // items (qd, hp): qd in {c, c+5, c+10} (13 qds x 50 hps = 650 items). ----
    if (tid < 250) {
        const int hp = tid % 50;
        const int c  = tid / 50;   // 0..4
        const int h0 = hp * 2;
        const float4 wqa = *(const float4*)(wq + h0 * 6);
        const float4 wqb = *(const float4*)(wq + h0 * 6 + 4);
        const float4 wqc = *(const float4*)(wq + h0 * 6 + 8);
        const float4 wka = *(const float4*)(wk + h0 * 6);
        const float4 wkb = *(const float4*)(wk + h0 * 6 + 4);
        const float4 wkc = *(const float4*)(wk + h0 * 6 + 8);
        const float4 wva = *(const float4*)(wv + h0 * 6);
        const float4 wvb = *(const float4*)(wv + h0 * 6 + 4);
        const float4 wvc = *(const float4*)(wv + h0 * 6 + 8);

        #pragma unroll
        for (int u = 0; u < 3; ++u) {
            const int qd = c + u * 5;
            if (qd <= 12) {
                const int tbase = qd * 4;
                // 12 independent x loads first (MLP)
                float4 xr[4][3];
                #pragma unroll
                for (int r = 0; r < 4; ++r) {
                    const int tc = (tbase + r < TT) ? (tbase + r) : (TT - 1);
                    const float* xp = xb + tc * CC + h0 * 6;   // 48B/lane, coalesced
                    xr[r][0] = *(const float4*)xp;
                    xr[r][1] = *(const float4*)(xp + 4);
                    xr[r][2] = *(const float4*)(xp + 8);
                }
                short4v vp0 = {0, 0, 0, 0};
                short4v vp1 = {0, 0, 0, 0};
                #pragma unroll
                for (int r = 0; r < 4; ++r) {
                    const int t = tbase + r;
                    const float4 xa = xr[r][0], xm = xr[r][1], xc = xr[r][2];
                    float q0 = xa.x*wqa.x + xa.y*wqa.y + xa.z*wqa.z + xa.w*wqa.w + xm.x*wqb.x + xm.y*wqb.y;
                    float q1 = xm.z*wqb.z + xm.w*wqb.w + xc.x*wqc.x + xc.y*wqc.y + xc.z*wqc.z + xc.w*wqc.w;
                    float k0 = xa.x*wka.x + xa.y*wka.y + xa.z*wka.z + xa.w*wka.w + xm.x*wkb.x + xm.y*wkb.y;
                    float k1 = xm.z*wkb.z + xm.w*wkb.w + xc.x*wkc.x + xc.y*wkc.y + xc.z*wkc.z + xc.w*wkc.w;
                    float v0 = xa.x*wva.x + xa.y*wva.y + xa.z*wva.z + xa.w*wva.w + xm.x*wvb.x + xm.y*wvb.y;
                    float v1 = xm.z*wvb.z + xm.w*wvb.w + xc.x*wvc.x + xc.y*wvc.y + xc.z*wvc.z + xc.w*wvc.w;
                    q0 *= kScale; q1 *= kScale;
                    if (t < TT) {
                        const int qg = (((h0 >> 3) ^ (t & 7)) << 3) + (h0 & 7);
                        *reinterpret_cast<unsigned*>(lds + OQ  + t * 128 + qg) =
                            (unsigned)f2bf(q0) | ((unsigned)f2bf(q1) << 16);
                        *reinterpret_cast<unsigned*>(lds + OKk + t * 128 + qg) =
                            (unsigned)f2bf(k0) | ((unsigned)f2bf(k1) << 16);
                        vp0[r] = (short)f2bf(v0);
                        vp1[r] = (short)f2bf(v1);
                    }
                }
                const int g = qd >> 1, half = (qd & 1) * 4;
                *reinterpret_cast<short4v*>(lds + OV + h0 * 64 + ((g ^ (h0 & 7)) << 3) + half) = vp0;
                *reinterpret_cast<short4v*>(lds + OV + (h0 + 1) * 64 + ((g ^ ((h0 + 1) & 7)) << 3) + half) = vp1;
            }
        }
    }
    __syncthreads();   // barrier 1: q,k,vT (+pads) ready

    const int wv_ = tid >> 6;
    const int lane = tid & 63;
    const int l15 = lane & 15, l4 = lane >> 4;

    // ---- phase 2: scores S = Q*K^T via MFMA, 10 causal tiles, write P direct ----
    for (int p = wv_; p < 10; p += NWAVES) {
        const int tm = (p >= 6) ? 3 : (p >= 3) ? 2 : (p >= 1) ? 1 : 0;
        const int sn = p - tm * (tm + 1) / 2;
        f32x4 acc = {0.f, 0.f, 0.f, 0.f};
        const int ar = tm * 16 + l15;   // q row (>=50: finite junk -> discarded)
        const int br = sn * 16 + l15;   // k row
        #pragma unroll
        for (int kk = 0; kk < 4; ++kk) {
            const int g = kk * 4 + l4;
            const short8 a  = *reinterpret_cast<const short8*>(lds + OQ  + ar * 128 + ((g ^ (ar & 7)) << 3));
            const short8 bb = *reinterpret_cast<const short8*>(lds + OKk + br * 128 + ((g ^ (br & 7)) << 3));
            acc = __builtin_amdgcn_mfma_f32_16x16x32_bf16(a, bb, acc, 0, 0, 0);
        }
        const int row0 = tm * 16 + l4 * 4;
        const int col = sn * 16 + l15;
        #pragma unroll
        for (int r = 0; r < 4; ++r) {
            const int row = row0 + r;
            lds[OP + row * 64 + (((col >> 3) ^ (row & 7)) << 3) + (col & 7)] = f2bf(acc[r]);
        }
    }
    __syncthreads();   // barrier 2: P scores ready

    // ---- phase 3: softmax, 4-lane group per row (all waves busy) ----
    {
        const int t = tid >> 2, ll = tid & 3;
        if (t < TT) {
            const int ga = (2 * ll) ^ (t & 7), gb = (2 * ll + 1) ^ (t & 7);
            const short8 pa = *reinterpret_cast<const short8*>(lds + OP + t * 64 + (ga << 3));
            const short8 pb = *reinterpret_cast<const short8*>(lds + OP + t * 64 + (gb << 3));
            float v[16];
            float mx = -3.4e38f;
            #pragma unroll
            for (int j = 0; j < 8; ++j) {
                const int s = 16 * ll + j;
                v[j] = bf2f((ushort_t)pa[j]);
                if (s <= t) mx = fmaxf(mx, v[j]);
            }
            #pragma unroll
            for (int j = 0; j < 8; ++j) {
                const int s = 16 * ll + 8 + j;
                v[8 + j] = bf2f((ushort_t)pb[j]);
                if (s <= t) mx = fmaxf(mx, v[8 + j]);
            }
            mx = fmaxf(mx, __shfl_xor(mx, 1));
            mx = fmaxf(mx, __shfl_xor(mx, 2));
            float sum = 0.f;
            #pragma unroll
            for (int j = 0; j < 16; ++j) {
                const int s = 16 * ll + j;
                const float e = (s <= t) ? __expf(v[j] - mx) : 0.f;
                v[j] = e;
                sum += e;
            }
            sum += __shfl_xor(sum, 1);
            sum += __shfl_xor(sum, 2);
            const float inv = 1.f / sum;
            short8 wa, wb;
            #pragma unroll
            for (int j = 0; j < 8; ++j) {
                wa[j] = (short)f2bf(v[j] * inv);
                wb[j] = (short)f2bf(v[8 + j] * inv);
            }
            *reinterpret_cast<short8*>(lds + OP + t * 64 + (ga << 3)) = wa;
            *reinterpret_cast<short8*>(lds + OP + t * 64 + (gb << 3)) = wb;
        }
    }
    __syncthreads();   // barrier 3: probabilities ready

    // ---- phase 4: O = P*V via MFMA, 4x7 tiles, K = 64 (P zeros past t) ----
    float* ob = out + (size_t)b * (TT * HH);
    for (int p = wv_; p < 28; p += NWAVES) {
        const int tm = p / 7, hn = p - tm * 7;
        f32x4 acc = {0.f, 0.f, 0.f, 0.f};
        const int ar = tm * 16 + l15;   // P row
        const int br = hn * 16 + l15;   // vT row (h); rows 100..111 zeroed
        #pragma unroll
        for (int kk = 0; kk < 2; ++kk) {
            const int g = kk * 4 + l4;
            const short8 a  = *reinterpret_cast<const short8*>(lds + OP + ar * 64 + ((g ^ (ar & 7)) << 3));
            const short8 bb = *reinterpret_cast<const short8*>(lds + OV + br * 64 + ((g ^ (br & 7)) << 3));
            acc = __builtin_amdgcn_mfma_f32_16x16x32_bf16(a, bb, acc, 0, 0, 0);
        }
        const int h = hn * 16 + l15;
        const int t0 = tm * 16 + l4 * 4;
        if (h < HH) {
            #pragma unroll
            for (int r = 0; r < 4; ++r) {
                const int t = t0 + r;
                if (t < TT) ob[t * HH + h] = acc[r];
            }
        }
    }
}

extern "C" void kernel_launch(void* const* d_in, const int* in_sizes, int n_in,
                              void* d_out, int out_size, void* d_ws, size_t ws_size,
                              hipStream_t stream) {
    const float* x  = (const float*)d_in[0];
    const float* wq = (const float*)d_in[1];
    const float* wk = (const float*)d_in[2];
    const float* wv = (const float*)d_in[3];
    float* out = (float*)d_out;
    headc_fused<<<dim3(BATCH), dim3(NTHR), 0, stream>>>(x, wq, wk, wv, out);
}